// Round 1
// baseline (680.778 us; speedup 1.0000x reference)
//
#include <hip/hip_runtime.h>

#define N_NODES 50000
#define N_EDGES 800000

// ---------------- CSR build ----------------

__global__ __launch_bounds__(256) void count_deg_k(const int* __restrict__ dst,
                                                   int* __restrict__ deg) {
  int e = blockIdx.x * 256 + threadIdx.x;
  if (e < N_EDGES) atomicAdd(&deg[dst[e]], 1);
}

__global__ __launch_bounds__(1024) void scan_k(const int* __restrict__ deg,
                                               int* __restrict__ offs,
                                               int* __restrict__ cur) {
  __shared__ int sums[1024];
  const int C = (N_NODES + 1023) / 1024;  // 49
  int t = threadIdx.x;
  int b = t * C;
  int e = b + C < N_NODES ? b + C : N_NODES;
  int s = 0;
  for (int i = b; i < e; ++i) s += deg[i];
  sums[t] = s;
  __syncthreads();
  // Hillis-Steele inclusive scan
  for (int off = 1; off < 1024; off <<= 1) {
    int v = 0;
    if (t >= off) v = sums[t - off];
    __syncthreads();
    sums[t] += v;
    __syncthreads();
  }
  int run = (t == 0) ? 0 : sums[t - 1];
  for (int i = b; i < e; ++i) {
    offs[i] = run;
    cur[i] = run;
    run += deg[i];
  }
}

__global__ __launch_bounds__(256) void fill_csr_k(const int* __restrict__ src,
                                                  const int* __restrict__ dst,
                                                  int* __restrict__ cur,
                                                  int* __restrict__ csr) {
  int e = blockIdx.x * 256 + threadIdx.x;
  if (e < N_EDGES) {
    int p = atomicAdd(&cur[dst[e]], 1);
    csr[p] = src[e];
  }
}

// ---------------- scatter-mean (one wave per node, CSR) ----------------

template <int D>
__global__ __launch_bounds__(256) void agg_mean_k(const float* __restrict__ in,
                                                  float* __restrict__ out,
                                                  const int* __restrict__ offs,
                                                  const int* __restrict__ deg,
                                                  const int* __restrict__ csr) {
  int node = (blockIdx.x * 256 + threadIdx.x) >> 6;
  int lane = threadIdx.x & 63;
  if (node >= N_NODES) return;
  int start = offs[node];
  int d = deg[node];
  if (D == 128) {
    float ax = 0.f, ay = 0.f;
    for (int e = 0; e < d; ++e) {
      int s = csr[start + e];
      float2 v = *(const float2*)(in + (size_t)s * 128 + lane * 2);
      ax += v.x;
      ay += v.y;
    }
    float inv = d > 0 ? 1.0f / (float)d : 0.0f;
    float2 o;
    o.x = ax * inv;
    o.y = ay * inv;
    *(float2*)(out + (size_t)node * 128 + lane * 2) = o;
  } else {
    float a = 0.f;
    for (int e = 0; e < d; ++e) {
      int s = csr[start + e];
      a += in[(size_t)s * 64 + lane];
    }
    float inv = d > 0 ? 1.0f / (float)d : 0.0f;
    out[(size_t)node * 64 + lane] = a * inv;
  }
}

// ---------------- skinny fp32 GEMM: C = A @ W^T (+bias) (+addend) ----------------
// A: M x K row-major, W: NOUT x K row-major, C: M x NOUT

template <int K, int NOUT, bool HAS_BIAS, bool HAS_ADD>
__global__ __launch_bounds__(256) void gemm_nt_k(const float* __restrict__ A,
                                                 const float* __restrict__ W,
                                                 const float* __restrict__ bias,
                                                 const float* __restrict__ add,
                                                 float* __restrict__ C, int M) {
  constexpr int BM = 64, BK = 32, TM = 8;
  constexpr int TN = NOUT / 32;  // 4 for NOUT=128, 2 for NOUT=64
  __shared__ float Ast[BK][BM + 4];    // K-major, padded: conflict-free b128 reads
  __shared__ float Wst[BK][NOUT + 4];
  int tid = threadIdx.x;
  int trow = tid >> 5;  // 0..7
  int tcol = tid & 31;  // 0..31
  int row0 = blockIdx.x * BM;
  float acc[TM][TN];
#pragma unroll
  for (int i = 0; i < TM; ++i)
#pragma unroll
    for (int j = 0; j < TN; ++j) acc[i][j] = 0.f;

  for (int k0 = 0; k0 < K; k0 += BK) {
    // stage A tile (BM x BK) transposed into LDS
#pragma unroll
    for (int s = tid; s < BM * (BK / 4); s += 256) {
      int r = s >> 3;   // row within tile
      int kv = s & 7;   // float4 index along k
      int g = row0 + r;
      float4 v = make_float4(0.f, 0.f, 0.f, 0.f);
      if (g < M) v = *(const float4*)(A + (size_t)g * K + k0 + kv * 4);
      Ast[kv * 4 + 0][r] = v.x;
      Ast[kv * 4 + 1][r] = v.y;
      Ast[kv * 4 + 2][r] = v.z;
      Ast[kv * 4 + 3][r] = v.w;
    }
    // stage W tile (NOUT x BK) transposed into LDS
#pragma unroll
    for (int s = tid; s < NOUT * (BK / 4); s += 256) {
      int r = s >> 3;
      int kv = s & 7;
      float4 v = *(const float4*)(W + (size_t)r * K + k0 + kv * 4);
      Wst[kv * 4 + 0][r] = v.x;
      Wst[kv * 4 + 1][r] = v.y;
      Wst[kv * 4 + 2][r] = v.z;
      Wst[kv * 4 + 3][r] = v.w;
    }
    __syncthreads();
#pragma unroll
    for (int kk = 0; kk < BK; ++kk) {
      float a[TM], b[TN];
      float4 a0 = *(const float4*)&Ast[kk][trow * TM];
      float4 a1 = *(const float4*)&Ast[kk][trow * TM + 4];
      a[0] = a0.x; a[1] = a0.y; a[2] = a0.z; a[3] = a0.w;
      a[4] = a1.x; a[5] = a1.y; a[6] = a1.z; a[7] = a1.w;
      if constexpr (TN == 4) {
        float4 bv = *(const float4*)&Wst[kk][tcol * TN];
        b[0] = bv.x; b[1] = bv.y; b[2] = bv.z; b[3] = bv.w;
      } else {
        float2 bv = *(const float2*)&Wst[kk][tcol * TN];
        b[0] = bv.x; b[1] = bv.y;
      }
#pragma unroll
      for (int i = 0; i < TM; ++i)
#pragma unroll
        for (int j = 0; j < TN; ++j) acc[i][j] += a[i] * b[j];
    }
    __syncthreads();
  }
  // epilogue
#pragma unroll
  for (int i = 0; i < TM; ++i) {
    int g = row0 + trow * TM + i;
    if (g >= M) continue;
    int col = tcol * TN;
    if constexpr (TN == 4) {
      float4 v = make_float4(acc[i][0], acc[i][1], acc[i][2], acc[i][3]);
      if constexpr (HAS_BIAS) {
        float4 bv = *(const float4*)(bias + col);
        v.x += bv.x; v.y += bv.y; v.z += bv.z; v.w += bv.w;
      }
      if constexpr (HAS_ADD) {
        float4 av = *(const float4*)(add + (size_t)g * NOUT + col);
        v.x += av.x; v.y += av.y; v.z += av.z; v.w += av.w;
      }
      *(float4*)(C + (size_t)g * NOUT + col) = v;
    } else {
      float2 v = make_float2(acc[i][0], acc[i][1]);
      if constexpr (HAS_BIAS) {
        float2 bv = *(const float2*)(bias + col);
        v.x += bv.x; v.y += bv.y;
      }
      if constexpr (HAS_ADD) {
        float2 av = *(const float2*)(add + (size_t)g * NOUT + col);
        v.x += av.x; v.y += av.y;
      }
      *(float2*)(C + (size_t)g * NOUT + col) = v;
    }
  }
}

// h2 = m2 + b2 + r2, N x 64, float4-vectorized
__global__ __launch_bounds__(256) void add3_k(const float* __restrict__ m,
                                              const float* __restrict__ b,
                                              const float* __restrict__ r,
                                              float* __restrict__ o) {
  int i = blockIdx.x * 256 + threadIdx.x;  // float4 index; total N_NODES*16
  if (i >= N_NODES * 16) return;
  int colv = i & 15;
  float4 mv = ((const float4*)m)[i];
  float4 rv = ((const float4*)r)[i];
  float4 bv = ((const float4*)b)[colv];
  float4 ov;
  ov.x = mv.x + bv.x + rv.x;
  ov.y = mv.y + bv.y + rv.y;
  ov.z = mv.z + bv.z + rv.z;
  ov.w = mv.w + bv.w + rv.w;
  ((float4*)o)[i] = ov;
}

extern "C" void kernel_launch(void* const* d_in, const int* in_sizes, int n_in,
                              void* d_out, int out_size, void* d_ws, size_t ws_size,
                              hipStream_t stream) {
  const float* x  = (const float*)d_in[0];
  const int* ei   = (const int*)d_in[1];
  const float* Wl1 = (const float*)d_in[2];
  const float* b1  = (const float*)d_in[3];
  const float* Wr1 = (const float*)d_in[4];
  const float* Wl2 = (const float*)d_in[5];
  const float* b2  = (const float*)d_in[6];
  const float* Wr2 = (const float*)d_in[7];
  const float* Wl3 = (const float*)d_in[8];
  const float* b3  = (const float*)d_in[9];
  const float* Wr3 = (const float*)d_in[10];
  float* out = (float*)d_out;

  const int* src = ei;            // edge_index[0]
  const int* dst = ei + N_EDGES;  // edge_index[1]

  char* ws = (char*)d_ws;
  size_t off = 0;
  auto take = [&](size_t bytes) {
    void* p = ws + off;
    off += (bytes + 255) & ~(size_t)255;
    return p;
  };
  int* deg  = (int*)take((size_t)N_NODES * 4);
  int* offs = (int*)take((size_t)N_NODES * 4);
  int* cur  = (int*)take((size_t)N_NODES * 4);
  int* csr  = (int*)take((size_t)N_EDGES * 4);
  float* A  = (float*)take((size_t)N_NODES * 128 * 4);
  float* B  = (float*)take((size_t)N_NODES * 128 * 4);
  float* Cb = (float*)take((size_t)N_NODES * 128 * 4);
  float* Db = (float*)take((size_t)N_NODES * 64 * 4);

  const int eb = (N_EDGES + 255) / 256;       // 3125
  const int ab = (N_NODES + 3) / 4;           // 12500 (4 waves/block, 1 node/wave)
  const int gg = (N_NODES + 63) / 64;         // 782

  // CSR build (reused by all 3 layers)
  hipMemsetAsync(deg, 0, (size_t)N_NODES * 4, stream);
  count_deg_k<<<eb, 256, 0, stream>>>(dst, deg);
  scan_k<<<1, 1024, 0, stream>>>(deg, offs, cur);
  fill_csr_k<<<eb, 256, 0, stream>>>(src, dst, cur, csr);

  // layer 1: aggregate x (128) then dual GEMM
  agg_mean_k<128><<<ab, 256, 0, stream>>>(x, A, offs, deg, csr);
  gemm_nt_k<128, 128, false, false><<<gg, 256, 0, stream>>>(x, Wr1, nullptr, nullptr, B, N_NODES);
  gemm_nt_k<128, 128, true, true><<<gg, 256, 0, stream>>>(A, Wl1, b1, B, Cb, N_NODES);  // h1

  // layer 2: project first (64-wide scatter), then aggregate
  gemm_nt_k<128, 64, false, false><<<gg, 256, 0, stream>>>(Cb, Wl2, nullptr, nullptr, A, N_NODES);  // p2
  gemm_nt_k<128, 64, false, false><<<gg, 256, 0, stream>>>(Cb, Wr2, nullptr, nullptr, B, N_NODES);  // r2
  agg_mean_k<64><<<ab, 256, 0, stream>>>(A, Db, offs, deg, csr);  // m2
  add3_k<<<3125, 256, 0, stream>>>(Db, b2, B, Cb);                // h2 (N x 64)

  // layer 3: aggregate first (64-wide), then dual GEMM
  agg_mean_k<64><<<ab, 256, 0, stream>>>(Cb, A, offs, deg, csr);  // m3
  gemm_nt_k<64, 128, false, false><<<gg, 256, 0, stream>>>(Cb, Wr3, nullptr, nullptr, B, N_NODES);  // t3
  gemm_nt_k<64, 128, true, true><<<gg, 256, 0, stream>>>(A, Wl3, b3, B, out, N_NODES);
}

// Round 2
// 423.727 us; speedup vs baseline: 1.6066x; 1.6066x over previous
//
#include <hip/hip_runtime.h>

#define N_NODES 50000
#define N_EDGES 800000
#define NB_SCAN 196  // ceil(N_NODES / 256)

// ---------------- CSR build ----------------

__global__ __launch_bounds__(256) void count_deg_k(const int* __restrict__ dst,
                                                   int* __restrict__ deg) {
  int e = blockIdx.x * 256 + threadIdx.x;
  if (e < N_EDGES) atomicAdd(&deg[dst[e]], 1);
}

// phase 1: per-block (256-elem chunk) sums
__global__ __launch_bounds__(256) void block_sum_k(const int* __restrict__ deg,
                                                   int* __restrict__ bsum) {
  int i = blockIdx.x * 256 + threadIdx.x;
  int v = (i < N_NODES) ? deg[i] : 0;
#pragma unroll
  for (int o = 32; o > 0; o >>= 1) v += __shfl_down(v, o, 64);
  __shared__ int s[4];
  if ((threadIdx.x & 63) == 0) s[threadIdx.x >> 6] = v;
  __syncthreads();
  if (threadIdx.x == 0) bsum[blockIdx.x] = s[0] + s[1] + s[2] + s[3];
}

// phase 2: scan the 196 block sums (single tiny block)
__global__ __launch_bounds__(256) void scan_bsum_k(const int* __restrict__ bsum,
                                                   int* __restrict__ boffs) {
  __shared__ int sh[256];
  int t = threadIdx.x;
  sh[t] = (t < NB_SCAN) ? bsum[t] : 0;
  __syncthreads();
  for (int o = 1; o < 256; o <<= 1) {
    int v = (t >= o) ? sh[t - o] : 0;
    __syncthreads();
    sh[t] += v;
    __syncthreads();
  }
  if (t < NB_SCAN) boffs[t] = (t == 0) ? 0 : sh[t - 1];
}

// phase 3: per-block local scan + block offset -> exclusive offsets
__global__ __launch_bounds__(256) void apply_scan_k(const int* __restrict__ deg,
                                                    const int* __restrict__ boffs,
                                                    int* __restrict__ offs,
                                                    int* __restrict__ cur) {
  __shared__ int sh[256];
  int t = threadIdx.x;
  int i = blockIdx.x * 256 + t;
  int v = (i < N_NODES) ? deg[i] : 0;
  sh[t] = v;
  __syncthreads();
  for (int o = 1; o < 256; o <<= 1) {
    int w = (t >= o) ? sh[t - o] : 0;
    __syncthreads();
    sh[t] += w;
    __syncthreads();
  }
  int excl = boffs[blockIdx.x] + ((t == 0) ? 0 : sh[t - 1]);
  if (i < N_NODES) {
    offs[i] = excl;
    cur[i] = excl;
  }
}

__global__ __launch_bounds__(256) void fill_csr_k(const int* __restrict__ src,
                                                  const int* __restrict__ dst,
                                                  int* __restrict__ cur,
                                                  int* __restrict__ csr) {
  int e = blockIdx.x * 256 + threadIdx.x;
  if (e < N_EDGES) {
    int p = atomicAdd(&cur[dst[e]], 1);
    csr[p] = src[e];
  }
}

// ---------------- mean aggregation: D/4 lanes per node, float4 gathers ----------------
// FUSE: out = mean + bias + addend (layer-2 h2 = m2 + b2 + r2)

template <int D, bool FUSE>
__global__ __launch_bounds__(256) void agg_mean_k(const float* __restrict__ in,
                                                  float* __restrict__ out,
                                                  const int* __restrict__ offs,
                                                  const int* __restrict__ deg,
                                                  const int* __restrict__ csr,
                                                  const float* __restrict__ bias,
                                                  const float* __restrict__ addend) {
  constexpr int L = D / 4;         // lanes per node (32 for D=128, 16 for D=64)
  constexpr int NPB = 256 / L;     // nodes per block
  int node = blockIdx.x * NPB + threadIdx.x / L;
  int lane = threadIdx.x & (L - 1);
  if (node >= N_NODES) return;
  int start = offs[node];
  int d = deg[node];
  float4 acc = make_float4(0.f, 0.f, 0.f, 0.f);
  int e = 0;
  for (; e + 1 < d; e += 2) {
    int s0 = csr[start + e];
    int s1 = csr[start + e + 1];
    float4 v0 = *(const float4*)(in + (size_t)s0 * D + lane * 4);
    float4 v1 = *(const float4*)(in + (size_t)s1 * D + lane * 4);
    acc.x += v0.x + v1.x;
    acc.y += v0.y + v1.y;
    acc.z += v0.z + v1.z;
    acc.w += v0.w + v1.w;
  }
  if (e < d) {
    int s0 = csr[start + e];
    float4 v0 = *(const float4*)(in + (size_t)s0 * D + lane * 4);
    acc.x += v0.x;
    acc.y += v0.y;
    acc.z += v0.z;
    acc.w += v0.w;
  }
  float inv = d > 0 ? 1.0f / (float)d : 0.0f;
  float4 o;
  o.x = acc.x * inv;
  o.y = acc.y * inv;
  o.z = acc.z * inv;
  o.w = acc.w * inv;
  if constexpr (FUSE) {
    float4 bv = *(const float4*)(bias + lane * 4);
    float4 av = *(const float4*)(addend + (size_t)node * D + lane * 4);
    o.x += bv.x + av.x;
    o.y += bv.y + av.y;
    o.z += bv.z + av.z;
    o.w += bv.w + av.w;
  }
  *(float4*)(out + (size_t)node * D + lane * 4) = o;
}

// ---------------- fused dual GEMM: C = A1@W1^T + A2@W2^T + bias ----------------
// A1,A2: M x K row-major; W1,W2: NOUT x K row-major; C: M x NOUT. NOUT=128.

template <int K>
__global__ __launch_bounds__(256) void dual_gemm_k(const float* __restrict__ A1,
                                                   const float* __restrict__ W1,
                                                   const float* __restrict__ A2,
                                                   const float* __restrict__ W2,
                                                   const float* __restrict__ bias,
                                                   float* __restrict__ C, int M) {
  constexpr int BM = 64, BK = 32, TM = 8, TN = 4, NOUT = 128;
  __shared__ float Ast[2][BK][BM + 4];
  __shared__ float Wst[2][BK][NOUT + 4];
  int tid = threadIdx.x;
  int trow = tid >> 5;  // 0..7
  int tcol = tid & 31;  // 0..31
  int row0 = blockIdx.x * BM;
  float acc[TM][TN];
#pragma unroll
  for (int i = 0; i < TM; ++i)
#pragma unroll
    for (int j = 0; j < TN; ++j) acc[i][j] = 0.f;

  for (int k0 = 0; k0 < K; k0 += BK) {
#pragma unroll
    for (int op = 0; op < 2; ++op) {
      const float* A = op ? A2 : A1;
      const float* W = op ? W2 : W1;
#pragma unroll
      for (int s = tid; s < BM * (BK / 4); s += 256) {
        int r = s >> 3;
        int kv = s & 7;
        int g = row0 + r;
        float4 v = make_float4(0.f, 0.f, 0.f, 0.f);
        if (g < M) v = *(const float4*)(A + (size_t)g * K + k0 + kv * 4);
        Ast[op][kv * 4 + 0][r] = v.x;
        Ast[op][kv * 4 + 1][r] = v.y;
        Ast[op][kv * 4 + 2][r] = v.z;
        Ast[op][kv * 4 + 3][r] = v.w;
      }
#pragma unroll
      for (int s = tid; s < NOUT * (BK / 4); s += 256) {
        int r = s >> 3;
        int kv = s & 7;
        float4 v = *(const float4*)(W + (size_t)r * K + k0 + kv * 4);
        Wst[op][kv * 4 + 0][r] = v.x;
        Wst[op][kv * 4 + 1][r] = v.y;
        Wst[op][kv * 4 + 2][r] = v.z;
        Wst[op][kv * 4 + 3][r] = v.w;
      }
    }
    __syncthreads();
#pragma unroll
    for (int kk = 0; kk < BK; ++kk) {
#pragma unroll
      for (int op = 0; op < 2; ++op) {
        float a[TM], b[TN];
        float4 a0 = *(const float4*)&Ast[op][kk][trow * TM];
        float4 a1 = *(const float4*)&Ast[op][kk][trow * TM + 4];
        a[0] = a0.x; a[1] = a0.y; a[2] = a0.z; a[3] = a0.w;
        a[4] = a1.x; a[5] = a1.y; a[6] = a1.z; a[7] = a1.w;
        float4 bv = *(const float4*)&Wst[op][kk][tcol * TN];
        b[0] = bv.x; b[1] = bv.y; b[2] = bv.z; b[3] = bv.w;
#pragma unroll
        for (int i = 0; i < TM; ++i)
#pragma unroll
          for (int j = 0; j < TN; ++j) acc[i][j] += a[i] * b[j];
      }
    }
    __syncthreads();
  }
#pragma unroll
  for (int i = 0; i < TM; ++i) {
    int g = row0 + trow * TM + i;
    if (g >= M) continue;
    int col = tcol * TN;
    float4 v = make_float4(acc[i][0], acc[i][1], acc[i][2], acc[i][3]);
    float4 bv = *(const float4*)(bias + col);
    v.x += bv.x; v.y += bv.y; v.z += bv.z; v.w += bv.w;
    *(float4*)(C + (size_t)g * NOUT + col) = v;
  }
}

// ---------------- layer-2 dual-output GEMM: O1 = A@Wl^T, O2 = A@Wr^T ----------------
// A: M x 128; Wl, Wr: 64 x 128; O1, O2: M x 64.

__global__ __launch_bounds__(256) void gemm_dualout_k(const float* __restrict__ A,
                                                      const float* __restrict__ Wl,
                                                      const float* __restrict__ Wr,
                                                      float* __restrict__ O1,
                                                      float* __restrict__ O2, int M) {
  constexpr int BM = 64, BK = 32, TM = 8, TN = 4, K = 128, NT = 128;
  __shared__ float Ast[BK][BM + 4];
  __shared__ float Wst[BK][NT + 4];
  int tid = threadIdx.x;
  int trow = tid >> 5;
  int tcol = tid & 31;
  int row0 = blockIdx.x * BM;
  float acc[TM][TN];
#pragma unroll
  for (int i = 0; i < TM; ++i)
#pragma unroll
    for (int j = 0; j < TN; ++j) acc[i][j] = 0.f;

  for (int k0 = 0; k0 < K; k0 += BK) {
#pragma unroll
    for (int s = tid; s < BM * (BK / 4); s += 256) {
      int r = s >> 3;
      int kv = s & 7;
      int g = row0 + r;
      float4 v = make_float4(0.f, 0.f, 0.f, 0.f);
      if (g < M) v = *(const float4*)(A + (size_t)g * K + k0 + kv * 4);
      Ast[kv * 4 + 0][r] = v.x;
      Ast[kv * 4 + 1][r] = v.y;
      Ast[kv * 4 + 2][r] = v.z;
      Ast[kv * 4 + 3][r] = v.w;
    }
#pragma unroll
    for (int s = tid; s < NT * (BK / 4); s += 256) {
      int r = s >> 3;  // 0..127: 0..63 -> Wl, 64..127 -> Wr
      int kv = s & 7;
      const float* Wp = (r < 64) ? (Wl + (size_t)r * K) : (Wr + (size_t)(r - 64) * K);
      float4 v = *(const float4*)(Wp + k0 + kv * 4);
      Wst[kv * 4 + 0][r] = v.x;
      Wst[kv * 4 + 1][r] = v.y;
      Wst[kv * 4 + 2][r] = v.z;
      Wst[kv * 4 + 3][r] = v.w;
    }
    __syncthreads();
#pragma unroll
    for (int kk = 0; kk < BK; ++kk) {
      float a[TM], b[TN];
      float4 a0 = *(const float4*)&Ast[kk][trow * TM];
      float4 a1 = *(const float4*)&Ast[kk][trow * TM + 4];
      a[0] = a0.x; a[1] = a0.y; a[2] = a0.z; a[3] = a0.w;
      a[4] = a1.x; a[5] = a1.y; a[6] = a1.z; a[7] = a1.w;
      float4 bv = *(const float4*)&Wst[kk][tcol * TN];
      b[0] = bv.x; b[1] = bv.y; b[2] = bv.z; b[3] = bv.w;
#pragma unroll
      for (int i = 0; i < TM; ++i)
#pragma unroll
        for (int j = 0; j < TN; ++j) acc[i][j] += a[i] * b[j];
    }
    __syncthreads();
  }
#pragma unroll
  for (int i = 0; i < TM; ++i) {
    int g = row0 + trow * TM + i;
    if (g >= M) continue;
    int col = tcol * TN;
    float4 v = make_float4(acc[i][0], acc[i][1], acc[i][2], acc[i][3]);
    if (col < 64) {
      *(float4*)(O1 + (size_t)g * 64 + col) = v;
    } else {
      *(float4*)(O2 + (size_t)g * 64 + (col - 64)) = v;
    }
  }
}

extern "C" void kernel_launch(void* const* d_in, const int* in_sizes, int n_in,
                              void* d_out, int out_size, void* d_ws, size_t ws_size,
                              hipStream_t stream) {
  const float* x   = (const float*)d_in[0];
  const int* ei    = (const int*)d_in[1];
  const float* Wl1 = (const float*)d_in[2];
  const float* b1  = (const float*)d_in[3];
  const float* Wr1 = (const float*)d_in[4];
  const float* Wl2 = (const float*)d_in[5];
  const float* b2  = (const float*)d_in[6];
  const float* Wr2 = (const float*)d_in[7];
  const float* Wl3 = (const float*)d_in[8];
  const float* b3  = (const float*)d_in[9];
  const float* Wr3 = (const float*)d_in[10];
  float* out = (float*)d_out;

  const int* src = ei;            // edge_index[0]
  const int* dst = ei + N_EDGES;  // edge_index[1]

  char* ws = (char*)d_ws;
  size_t off = 0;
  auto take = [&](size_t bytes) {
    void* p = ws + off;
    off += (bytes + 255) & ~(size_t)255;
    return p;
  };
  int* deg   = (int*)take((size_t)N_NODES * 4);
  int* offs  = (int*)take((size_t)N_NODES * 4);
  int* cur   = (int*)take((size_t)N_NODES * 4);
  int* csr   = (int*)take((size_t)N_EDGES * 4);
  int* bsum  = (int*)take((size_t)NB_SCAN * 4);
  int* boffs = (int*)take((size_t)NB_SCAN * 4);
  float* A   = (float*)take((size_t)N_NODES * 128 * 4);  // agg buffer (also m3)
  float* Cb  = (float*)take((size_t)N_NODES * 128 * 4);  // h1, then h2 (Nx64)
  float* P   = (float*)take((size_t)N_NODES * 64 * 4);   // p2 = h1 @ Wl2^T
  float* R   = (float*)take((size_t)N_NODES * 64 * 4);   // r2 = h1 @ Wr2^T

  const int eb = (N_EDGES + 255) / 256;  // 3125
  const int gg = (N_NODES + 63) / 64;    // 782

  // CSR build (parallel scan)
  hipMemsetAsync(deg, 0, (size_t)N_NODES * 4, stream);
  count_deg_k<<<eb, 256, 0, stream>>>(dst, deg);
  block_sum_k<<<NB_SCAN, 256, 0, stream>>>(deg, bsum);
  scan_bsum_k<<<1, 256, 0, stream>>>(bsum, boffs);
  apply_scan_k<<<NB_SCAN, 256, 0, stream>>>(deg, boffs, offs, cur);
  fill_csr_k<<<eb, 256, 0, stream>>>(src, dst, cur, csr);

  // layer 1: m1 = mean(x); h1 = m1@Wl1^T + x@Wr1^T + b1
  agg_mean_k<128, false><<<6250, 256, 0, stream>>>(x, A, offs, deg, csr, nullptr, nullptr);
  dual_gemm_k<128><<<gg, 256, 0, stream>>>(A, Wl1, x, Wr1, b1, Cb, N_NODES);

  // layer 2 (project-then-aggregate): p2 = h1@Wl2^T, r2 = h1@Wr2^T; h2 = mean(p2) + b2 + r2
  gemm_dualout_k<<<gg, 256, 0, stream>>>(Cb, Wl2, Wr2, P, R, N_NODES);
  agg_mean_k<64, true><<<3125, 256, 0, stream>>>(P, Cb, offs, deg, csr, b2, R);  // h2 in Cb (Nx64)

  // layer 3 (aggregate-then-project): m3 = mean(h2); out = m3@Wl3^T + h2@Wr3^T + b3
  agg_mean_k<64, false><<<3125, 256, 0, stream>>>(Cb, A, offs, deg, csr, nullptr, nullptr);
  dual_gemm_k<64><<<gg, 256, 0, stream>>>(A, Wl3, Cb, Wr3, b3, out, N_NODES);
}